// Round 5
// baseline (179.670 us; speedup 1.0000x reference)
//
#include <hip/hip_runtime.h>
#include <math.h>

// Problem constants
#define B 2
#define N 8192
#define M 8192
#define NPTS (B*N)
#define VD 64
#define VH 128
#define VW 128
#define VVOX (VD*VH*VW)         // 1048576 voxels per batch
#define DHH 512
#define DWW 512
#define DPIX (DHH*DWW)

// Chamfer tiling
#define QT 8
#define SEGS 32
#define TSEG (M/SEGS)           // 256 targets per block

// Workspace layout (float indices). No contended atomics; the only atomic is
// the phase2 completion ticket (1 op/block, 576 total).
#define OFF_WH_P   0                        // B*VVOX floats: (w,h)-eroded pred
#define OFF_WH_G   2097152                  // B*VVOX floats: (w,h)-eroded gt
#define OFF_CHPART 4194304                  // [2 dirs][32 segs][16384 q] partial mins
#define OFF_PCL    5242880                  // [3 terms][512 blk] cldice partials
#define OFF_PDE    5244416                  // [6 terms][256 blk] depth partials
#define OFF_PCH    5245952                  // [64] chamfer block partial sums
#define OFF_TICKET 5246016                  // int completion counter

__device__ __forceinline__ float blockSum(float v, volatile float* sm) {
    #pragma unroll
    for (int o = 32; o > 0; o >>= 1) v += __shfl_down(v, o, 64);
    int lane = threadIdx.x & 63, wid = threadIdx.x >> 6;
    __syncthreads();
    if (lane == 0) sm[wid] = v;
    __syncthreads();
    return sm[0] + sm[1] + sm[2] + sm[3];
}

__device__ __forceinline__ float min3f(float a, float b, float c) {
    return fminf(a, fminf(b, c));
}

__device__ __forceinline__ float sumRange(const float* p, int n, volatile float* sm) {
    float s = 0.f;
    for (int t = threadIdx.x; t < n; t += 256) s += p[t];
    return blockSum(s, sm);
}

// ============================ PHASE 1 =====================================
// blocks [0,512): chamfer partial mins (inline query/target packing)
// blocks [512,2560): erodeA — separable (w,h) 3x3 min of both volumes
// blocks [2560,2816): depth-loss partial sums
__global__ __launch_bounds__(256) void k_phase1(const float* __restrict__ pc,
                                                const float* __restrict__ gp,
                                                const float* __restrict__ pv,
                                                const float* __restrict__ gv,
                                                const float* __restrict__ pd,
                                                const float* __restrict__ gd,
                                                const float* __restrict__ mk,
                                                float* ws) {
    __shared__ float4 smem[TSEG];            // chamfer targets / reduce scratch
    unsigned int bb = blockIdx.x;
    if (bb == 0 && threadIdx.x == 0) *(int*)(ws + OFF_TICKET) = 0;

    if (bb < 512) {
        // ---------------- chamfer ----------------
        int dir  = bb >> 8;                  // 0: pred->gt, 1: gt->pred
        int rem  = bb & 255;
        int seg  = rem >> 3;
        int qblk = rem & 7;
        const float* Q = dir ? gp : pc;
        const float* T = dir ? pc : gp;
        int qbase = qblk * (256*QT);         // 2048-query chunk, batch-aligned
        int b = qbase >> 13;

        {   // stage + pack 256 targets into LDS
            int t = b*M + seg*TSEG + threadIdx.x;
            float x = T[3*t], y = T[3*t+1], z = T[3*t+2];
            smem[threadIdx.x] = make_float4(x, y, z, x*x + y*y + z*z);
        }
        float nx[QT], ny[QT], nz[QT], q2[QT], dmin[QT];
        #pragma unroll
        for (int k = 0; k < QT; ++k) {
            int i = qbase + k*256 + threadIdx.x;
            float x = Q[3*i], y = Q[3*i+1], z = Q[3*i+2];
            nx[k] = -2.f*x; ny[k] = -2.f*y; nz[k] = -2.f*z;
            q2[k] = x*x + y*y + z*z; dmin[k] = INFINITY;
        }
        __syncthreads();
        #pragma unroll 4
        for (int j = 0; j < TSEG; ++j) {
            float4 tv = smem[j];             // wave-uniform -> LDS broadcast
            #pragma unroll
            for (int k = 0; k < QT; ++k) {
                float d = fmaf(tv.x, nx[k], fmaf(tv.y, ny[k], fmaf(tv.z, nz[k], tv.w)));
                dmin[k] = fminf(dmin[k], d);
            }
        }
        float* part = ws + OFF_CHPART + dir*(SEGS*NPTS) + seg*NPTS + qbase;
        #pragma unroll
        for (int k = 0; k < QT; ++k)
            part[k*256 + threadIdx.x] = dmin[k] + q2[k];

    } else if (bb < 2560) {
        // ---------------- erodeA: (w,h) 3x3 min, both volumes ----------------
        int r0 = (bb - 512) * 8 + (threadIdx.x >> 5);  // global row [0,16384)
        int q  = threadIdx.x & 31;
        int w  = q * 4;
        int b  = r0 >> 13;
        int rb = r0 & 8191;
        int d  = rb >> 7;
        int h  = rb & 127;
        int rowOff = b*VVOX + d*(VH*VW) + h*VW;
        int up = (h > 0)   ? -VW : 0;        // clamp == SAME(+inf) for min
        int dn = (h < 127) ?  VW : 0;

        float4 om[2];
        const float* vols[2] = {pv, gv};
        #pragma unroll
        for (int a = 0; a < 2; ++a) {
            const float* row = vols[a] + rowOff;
            float4 acc = make_float4(INFINITY, INFINITY, INFINITY, INFINITY);
            #pragma unroll
            for (int rr = 0; rr < 3; ++rr) {
                const float* rw = row + (rr == 0 ? up : (rr == 2 ? dn : 0));
                float4 c = *(const float4*)(rw + w);
                float l = (q > 0)  ? rw[w-1] : c.x;
                float r = (q < 31) ? rw[w+4] : c.w;
                acc.x = fminf(acc.x, min3f(l,   c.x, c.y));
                acc.y = fminf(acc.y, min3f(c.x, c.y, c.z));
                acc.z = fminf(acc.z, min3f(c.y, c.z, c.w));
                acc.w = fminf(acc.w, min3f(c.z, c.w, r));
            }
            om[a] = acc;
        }
        ((float4*)(ws + OFF_WH_P + rowOff))[q] = om[0];
        ((float4*)(ws + OFF_WH_G + rowOff))[q] = om[1];

    } else {
        // ---------------- depth partials ----------------
        volatile float* sm = (volatile float*)smem;
        int idx0 = bb - 2560;                // [0,256)
        int b   = idx0 >> 7;
        int blk = idx0 & 127;
        const float* pb = pd + b * DPIX;
        const float* gb = gd + b * DPIX;
        const float* mb = mk + b * DPIX;
        float sg = 0, sg2 = 0, gx = 0, gy = 0, num = 0, den = 0;
        #pragma unroll
        for (int k = 0; k < 8; ++k) {
            int idx = (blk*8 + k)*256 + threadIdx.x;   // [0, DPIX)
            int h = idx >> 9;
            int w = idx & 511;
            float p = pb[idx], g = gb[idx], m = mb[idx];
            float lgv = logf(p + 0.1f) - logf(g + 0.1f);
            sg += lgv; sg2 += lgv * lgv;
            if (h < DHH - 1) {
                float p2 = pb[idx + DWW], g2 = gb[idx + DWW];
                gx += fabsf(fabsf(p - p2) - fabsf(g - g2));
            }
            if (w < DWW - 1) {
                float p2 = pb[idx + 1], g2 = gb[idx + 1];
                gy += fabsf(fabsf(p - p2) - fabsf(g - g2));
            }
            num += fabsf(p - g) * m;
            den += m;
        }
        float a;
        float* part = ws + OFF_PDE;          // [6][256]
        a = blockSum(sg,  sm); if (threadIdx.x == 0) part[       idx0] = a;
        a = blockSum(sg2, sm); if (threadIdx.x == 0) part[256  + idx0] = a;
        a = blockSum(gx,  sm); if (threadIdx.x == 0) part[512  + idx0] = a;
        a = blockSum(gy,  sm); if (threadIdx.x == 0) part[768  + idx0] = a;
        a = blockSum(num, sm); if (threadIdx.x == 0) part[1024 + idx0] = a;
        a = blockSum(den, sm); if (threadIdx.x == 0) part[1280 + idx0] = a;
    }
}

// ============================ PHASE 2 =====================================
// blocks [0,64): chamfer redmin; blocks [64,576): erodeB.
// Last-finishing block (device-scope ticket) performs the final combine.
#define P2_BLOCKS 576
__global__ __launch_bounds__(256) void k_phase2(float* ws, const int* iter,
                                                float* out) {
    __shared__ float sm[4];
    __shared__ int amLast;
    unsigned int bb = blockIdx.x;

    if (bb < 64) {
        // ---------------- chamfer redmin: min over segs, sum 512 queries ----
        int dir = bb >> 5;
        int blk = bb & 31;
        const float* base = ws + OFF_CHPART + dir*(SEGS*NPTS) + blk*512;
        float s = 0.f;
        #pragma unroll
        for (int u = 0; u < 2; ++u) {
            int t = u*256 + threadIdx.x;
            float m = INFINITY;
            #pragma unroll
            for (int sg = 0; sg < SEGS; ++sg) m = fminf(m, base[sg*NPTS + t]);
            s += m;
        }
        float a = blockSum(s, sm);
        if (threadIdx.x == 0) ws[OFF_PCH + bb] = a;
    } else {
        // ---------------- erodeB: d-min + sigmoid + clDice partials ---------
        int idx0 = bb - 64;                  // [0,512)
        const float4* whP = (const float4*)(ws + OFF_WH_P);
        const float4* whG = (const float4*)(ws + OFF_WH_G);
        int b   = idx0 >> 8;
        int blk = idx0 & 255;
        float li = 0.f, lp = 0.f, lg = 0.f;
        #pragma unroll
        for (int k = 0; k < 4; ++k) {
            int f4 = b*(VVOX/4) + (blk*4 + k)*256 + threadIdx.x;
            int d  = (f4 >> 12) & 63;        // 4096 float4 per d-plane
            int up = (d > 0)  ? -4096 : 0;
            int dn = (d < 63) ?  4096 : 0;
            float4 p0 = whP[f4+up], p1 = whP[f4], p2 = whP[f4+dn];
            float4 g0 = whG[f4+up], g1 = whG[f4], g2 = whG[f4+dn];
            float4 mp = make_float4(min3f(p0.x,p1.x,p2.x), min3f(p0.y,p1.y,p2.y),
                                    min3f(p0.z,p1.z,p2.z), min3f(p0.w,p1.w,p2.w));
            float4 mg = make_float4(min3f(g0.x,g1.x,g2.x), min3f(g0.y,g1.y,g2.y),
                                    min3f(g0.z,g1.z,g2.z), min3f(g0.w,g1.w,g2.w));
            float4 ps = make_float4(1.f/(1.f+__expf(-mp.x)), 1.f/(1.f+__expf(-mp.y)),
                                    1.f/(1.f+__expf(-mp.z)), 1.f/(1.f+__expf(-mp.w)));
            li += ps.x*mg.x + ps.y*mg.y + ps.z*mg.z + ps.w*mg.w;
            lp += ps.x + ps.y + ps.z + ps.w;
            lg += mg.x + mg.y + mg.z + mg.w;
        }
        float a;
        float* part = ws + OFF_PCL;          // [3][512]
        a = blockSum(li, sm); if (threadIdx.x == 0) part[        idx0] = a;
        a = blockSum(lp, sm); if (threadIdx.x == 0) part[512  + idx0] = a;
        a = blockSum(lg, sm); if (threadIdx.x == 0) part[1024 + idx0] = a;
    }

    // ---------------- completion ticket; last block combines ----------------
    __threadfence();
    if (threadIdx.x == 0) {
        int t = __hip_atomic_fetch_add((int*)(ws + OFF_TICKET), 1,
                                       __ATOMIC_ACQ_REL, __HIP_MEMORY_SCOPE_AGENT);
        amLast = (t == P2_BLOCKS - 1);
    }
    __syncthreads();
    if (!amLast) return;
    __threadfence();

    float sch = sumRange(ws + OFF_PCH, 64, sm);
    float i0  = sumRange(ws + OFF_PCL,        256, sm);
    float i1  = sumRange(ws + OFF_PCL + 256,  256, sm);
    float p0  = sumRange(ws + OFF_PCL + 512,  256, sm);
    float p1  = sumRange(ws + OFF_PCL + 768,  256, sm);
    float g0  = sumRange(ws + OFF_PCL + 1024, 256, sm);
    float g1  = sumRange(ws + OFF_PCL + 1280, 256, sm);
    float sg0 = sumRange(ws + OFF_PDE,        128, sm);
    float sg1 = sumRange(ws + OFF_PDE + 128,  128, sm);
    float s20 = sumRange(ws + OFF_PDE + 256,  128, sm);
    float s21 = sumRange(ws + OFF_PDE + 384,  128, sm);
    float gx  = sumRange(ws + OFF_PDE + 512,  256, sm);
    float gy  = sumRange(ws + OFF_PDE + 768,  256, sm);
    float num = sumRange(ws + OFF_PDE + 1024, 256, sm);
    float den = sumRange(ws + OFF_PDE + 1280, 256, sm);
    if (threadIdx.x != 0) return;

    float chamfer = sch / (float)NPTS;       // (sum_minP + sum_minG)/NPTS
    float dsum = (2.f*i0 + 1e-5f) / (p0 + g0 + 1e-5f)
               + (2.f*i1 + 1e-5f) / (p1 + g1 + 1e-5f);
    float cldice = 1.f - 0.5f * dsum;
    float silog = 0.f;
    {
        float gm = sg0 / (float)DPIX;
        float gv = s20 / (float)DPIX - gm*gm;
        silog += 10.f*0.5f*gv + 10.f*0.5f*gm*gm;
        gm = sg1 / (float)DPIX;
        gv = s21 / (float)DPIX - gm*gm;
        silog += 10.f*0.5f*gv + 10.f*0.5f*gm*gm;
    }
    float grad_l1 = gx / (float)(B*(DHH-1)*DWW) + gy / (float)(B*DHH*(DWW-1));
    float mask_l1 = num / (den + 1e-8f);
    float dloss = silog + grad_l1 + mask_l1;
    int it = iter[0]; if (it < 1) it = 1;
    float gamma1 = 2.f * logf((float)it / 20000.f);
    out[0] = gamma1 * chamfer + 0.5f * cldice + 0.01f * dloss;
}

extern "C" void kernel_launch(void* const* d_in, const int* in_sizes, int n_in,
                              void* d_out, int out_size, void* d_ws, size_t ws_size,
                              hipStream_t stream) {
    const float* pc  = (const float*)d_in[0];
    const float* pv  = (const float*)d_in[1];
    const float* pd  = (const float*)d_in[2];
    const float* gp  = (const float*)d_in[3];
    const float* gvv = (const float*)d_in[4];
    const float* gd  = (const float*)d_in[5];
    const float* mk  = (const float*)d_in[6];
    const int*   it  = (const int*)d_in[7];
    float* ws  = (float*)d_ws;
    float* out = (float*)d_out;

    k_phase1<<<2816, 256, 0, stream>>>(pc, gp, pv, gvv, pd, gd, mk, ws);
    k_phase2<<<P2_BLOCKS, 256, 0, stream>>>(ws, it, out);
}

// Round 6
// 120.014 us; speedup vs baseline: 1.4971x; 1.4971x over previous
//
#include <hip/hip_runtime.h>
#include <math.h>

// Problem constants
#define B 2
#define N 8192
#define M 8192
#define NPTS (B*N)
#define VD 64
#define VH 128
#define VW 128
#define VVOX (VD*VH*VW)         // 1048576 voxels per batch
#define DHH 512
#define DWW 512
#define DPIX (DHH*DWW)

// Chamfer tiling
#define QT 8
#define SEGS 32
#define TSEG (M/SEGS)           // 256 targets per block

// Workspace layout (float indices). NO atomics, NO device-scope fences
// (agent-scope fence == L2 writeback on gfx950 multi-XCD -> ~70us of stall
// when issued per-block; kernel boundaries give visibility for free).
#define OFF_WH_P   0                        // B*VVOX floats: (w,h)-eroded pred
#define OFF_WH_G   2097152                  // B*VVOX floats: (w,h)-eroded gt
#define OFF_CHPART 4194304                  // [2 dirs][32 segs][16384 q] partial mins
#define OFF_PCL    5242880                  // [3 terms][512 blk] cldice partials
#define OFF_PDE    5244416                  // [6 terms][256 blk] depth partials
#define OFF_PCH    5245952                  // [64] chamfer block partial sums

__device__ __forceinline__ float blockSum(float v, volatile float* sm) {
    #pragma unroll
    for (int o = 32; o > 0; o >>= 1) v += __shfl_down(v, o, 64);
    int lane = threadIdx.x & 63, wid = threadIdx.x >> 6;
    __syncthreads();
    if (lane == 0) sm[wid] = v;
    __syncthreads();
    return sm[0] + sm[1] + sm[2] + sm[3];
}

__device__ __forceinline__ float min3f(float a, float b, float c) {
    return fminf(a, fminf(b, c));
}

__device__ __forceinline__ float sumRange(const float* p, int n, volatile float* sm) {
    float s = 0.f;
    for (int t = threadIdx.x; t < n; t += 256) s += p[t];
    return blockSum(s, sm);
}

// ============================ PHASE 1 =====================================
// blocks [0,512): chamfer partial mins (inline query/target packing)
// blocks [512,2560): erodeA — separable (w,h) 3x3 min of both volumes
// blocks [2560,2816): depth-loss partial sums
__global__ __launch_bounds__(256) void k_phase1(const float* __restrict__ pc,
                                                const float* __restrict__ gp,
                                                const float* __restrict__ pv,
                                                const float* __restrict__ gv,
                                                const float* __restrict__ pd,
                                                const float* __restrict__ gd,
                                                const float* __restrict__ mk,
                                                float* ws) {
    __shared__ float4 smem[TSEG];            // chamfer targets / reduce scratch
    unsigned int bb = blockIdx.x;

    if (bb < 512) {
        // ---------------- chamfer ----------------
        int dir  = bb >> 8;                  // 0: pred->gt, 1: gt->pred
        int rem  = bb & 255;
        int seg  = rem >> 3;
        int qblk = rem & 7;
        const float* Q = dir ? gp : pc;
        const float* T = dir ? pc : gp;
        int qbase = qblk * (256*QT);         // 2048-query chunk, batch-aligned
        int b = qbase >> 13;

        {   // stage + pack 256 targets into LDS
            int t = b*M + seg*TSEG + threadIdx.x;
            float x = T[3*t], y = T[3*t+1], z = T[3*t+2];
            smem[threadIdx.x] = make_float4(x, y, z, x*x + y*y + z*z);
        }
        float nx[QT], ny[QT], nz[QT], q2[QT], dmin[QT];
        #pragma unroll
        for (int k = 0; k < QT; ++k) {
            int i = qbase + k*256 + threadIdx.x;
            float x = Q[3*i], y = Q[3*i+1], z = Q[3*i+2];
            nx[k] = -2.f*x; ny[k] = -2.f*y; nz[k] = -2.f*z;
            q2[k] = x*x + y*y + z*z; dmin[k] = INFINITY;
        }
        __syncthreads();
        #pragma unroll 4
        for (int j = 0; j < TSEG; ++j) {
            float4 tv = smem[j];             // wave-uniform -> LDS broadcast
            #pragma unroll
            for (int k = 0; k < QT; ++k) {
                float d = fmaf(tv.x, nx[k], fmaf(tv.y, ny[k], fmaf(tv.z, nz[k], tv.w)));
                dmin[k] = fminf(dmin[k], d);
            }
        }
        float* part = ws + OFF_CHPART + dir*(SEGS*NPTS) + seg*NPTS + qbase;
        #pragma unroll
        for (int k = 0; k < QT; ++k)
            part[k*256 + threadIdx.x] = dmin[k] + q2[k];

    } else if (bb < 2560) {
        // ---------------- erodeA: (w,h) 3x3 min, both volumes ----------------
        int r0 = (bb - 512) * 8 + (threadIdx.x >> 5);  // global row [0,16384)
        int q  = threadIdx.x & 31;
        int w  = q * 4;
        int b  = r0 >> 13;
        int rb = r0 & 8191;
        int d  = rb >> 7;
        int h  = rb & 127;
        int rowOff = b*VVOX + d*(VH*VW) + h*VW;
        int up = (h > 0)   ? -VW : 0;        // clamp == SAME(+inf) for min
        int dn = (h < 127) ?  VW : 0;

        float4 om[2];
        const float* vols[2] = {pv, gv};
        #pragma unroll
        for (int a = 0; a < 2; ++a) {
            const float* row = vols[a] + rowOff;
            float4 acc = make_float4(INFINITY, INFINITY, INFINITY, INFINITY);
            #pragma unroll
            for (int rr = 0; rr < 3; ++rr) {
                const float* rw = row + (rr == 0 ? up : (rr == 2 ? dn : 0));
                float4 c = *(const float4*)(rw + w);
                float l = (q > 0)  ? rw[w-1] : c.x;
                float r = (q < 31) ? rw[w+4] : c.w;
                acc.x = fminf(acc.x, min3f(l,   c.x, c.y));
                acc.y = fminf(acc.y, min3f(c.x, c.y, c.z));
                acc.z = fminf(acc.z, min3f(c.y, c.z, c.w));
                acc.w = fminf(acc.w, min3f(c.z, c.w, r));
            }
            om[a] = acc;
        }
        ((float4*)(ws + OFF_WH_P + rowOff))[q] = om[0];
        ((float4*)(ws + OFF_WH_G + rowOff))[q] = om[1];

    } else {
        // ---------------- depth partials ----------------
        volatile float* sm = (volatile float*)smem;
        int idx0 = bb - 2560;                // [0,256)
        int b   = idx0 >> 7;
        int blk = idx0 & 127;
        const float* pb = pd + b * DPIX;
        const float* gb = gd + b * DPIX;
        const float* mb = mk + b * DPIX;
        float sg = 0, sg2 = 0, gx = 0, gy = 0, num = 0, den = 0;
        #pragma unroll
        for (int k = 0; k < 8; ++k) {
            int idx = (blk*8 + k)*256 + threadIdx.x;   // [0, DPIX)
            int h = idx >> 9;
            int w = idx & 511;
            float p = pb[idx], g = gb[idx], m = mb[idx];
            float lgv = logf(p + 0.1f) - logf(g + 0.1f);
            sg += lgv; sg2 += lgv * lgv;
            if (h < DHH - 1) {
                float p2 = pb[idx + DWW], g2 = gb[idx + DWW];
                gx += fabsf(fabsf(p - p2) - fabsf(g - g2));
            }
            if (w < DWW - 1) {
                float p2 = pb[idx + 1], g2 = gb[idx + 1];
                gy += fabsf(fabsf(p - p2) - fabsf(g - g2));
            }
            num += fabsf(p - g) * m;
            den += m;
        }
        float a;
        float* part = ws + OFF_PDE;          // [6][256]
        a = blockSum(sg,  sm); if (threadIdx.x == 0) part[       idx0] = a;
        a = blockSum(sg2, sm); if (threadIdx.x == 0) part[256  + idx0] = a;
        a = blockSum(gx,  sm); if (threadIdx.x == 0) part[512  + idx0] = a;
        a = blockSum(gy,  sm); if (threadIdx.x == 0) part[768  + idx0] = a;
        a = blockSum(num, sm); if (threadIdx.x == 0) part[1024 + idx0] = a;
        a = blockSum(den, sm); if (threadIdx.x == 0) part[1280 + idx0] = a;
    }
}

// ============================ PHASE 2 =====================================
// blocks [0,64): chamfer redmin; blocks [64,576): erodeB. Plain stores only.
__global__ __launch_bounds__(256) void k_phase2(float* ws) {
    __shared__ float sm[4];
    unsigned int bb = blockIdx.x;

    if (bb < 64) {
        // ---------------- chamfer redmin: min over segs, sum 512 queries ----
        int dir = bb >> 5;
        int blk = bb & 31;
        const float* base = ws + OFF_CHPART + dir*(SEGS*NPTS) + blk*512;
        float s = 0.f;
        #pragma unroll
        for (int u = 0; u < 2; ++u) {
            int t = u*256 + threadIdx.x;
            float m = INFINITY;
            #pragma unroll
            for (int sg = 0; sg < SEGS; ++sg) m = fminf(m, base[sg*NPTS + t]);
            s += m;
        }
        float a = blockSum(s, sm);
        if (threadIdx.x == 0) ws[OFF_PCH + bb] = a;
    } else {
        // ---------------- erodeB: d-min + sigmoid + clDice partials ---------
        int idx0 = bb - 64;                  // [0,512)
        const float4* whP = (const float4*)(ws + OFF_WH_P);
        const float4* whG = (const float4*)(ws + OFF_WH_G);
        int b   = idx0 >> 8;
        int blk = idx0 & 255;
        float li = 0.f, lp = 0.f, lg = 0.f;
        #pragma unroll
        for (int k = 0; k < 4; ++k) {
            int f4 = b*(VVOX/4) + (blk*4 + k)*256 + threadIdx.x;
            int d  = (f4 >> 12) & 63;        // 4096 float4 per d-plane
            int up = (d > 0)  ? -4096 : 0;
            int dn = (d < 63) ?  4096 : 0;
            float4 p0 = whP[f4+up], p1 = whP[f4], p2 = whP[f4+dn];
            float4 g0 = whG[f4+up], g1 = whG[f4], g2 = whG[f4+dn];
            float4 mp = make_float4(min3f(p0.x,p1.x,p2.x), min3f(p0.y,p1.y,p2.y),
                                    min3f(p0.z,p1.z,p2.z), min3f(p0.w,p1.w,p2.w));
            float4 mg = make_float4(min3f(g0.x,g1.x,g2.x), min3f(g0.y,g1.y,g2.y),
                                    min3f(g0.z,g1.z,g2.z), min3f(g0.w,g1.w,g2.w));
            float4 ps = make_float4(1.f/(1.f+__expf(-mp.x)), 1.f/(1.f+__expf(-mp.y)),
                                    1.f/(1.f+__expf(-mp.z)), 1.f/(1.f+__expf(-mp.w)));
            li += ps.x*mg.x + ps.y*mg.y + ps.z*mg.z + ps.w*mg.w;
            lp += ps.x + ps.y + ps.z + ps.w;
            lg += mg.x + mg.y + mg.z + mg.w;
        }
        float a;
        float* part = ws + OFF_PCL;          // [3][512]
        a = blockSum(li, sm); if (threadIdx.x == 0) part[        idx0] = a;
        a = blockSum(lp, sm); if (threadIdx.x == 0) part[512  + idx0] = a;
        a = blockSum(lg, sm); if (threadIdx.x == 0) part[1024 + idx0] = a;
    }
}

// ============================ FINAL =======================================
__global__ __launch_bounds__(256) void k_final(const float* ws, const int* iter,
                                               float* out) {
    __shared__ float sm[4];
    float sch = sumRange(ws + OFF_PCH, 64, sm);
    float i0  = sumRange(ws + OFF_PCL,        256, sm);
    float i1  = sumRange(ws + OFF_PCL + 256,  256, sm);
    float p0  = sumRange(ws + OFF_PCL + 512,  256, sm);
    float p1  = sumRange(ws + OFF_PCL + 768,  256, sm);
    float g0  = sumRange(ws + OFF_PCL + 1024, 256, sm);
    float g1  = sumRange(ws + OFF_PCL + 1280, 256, sm);
    float sg0 = sumRange(ws + OFF_PDE,        128, sm);
    float sg1 = sumRange(ws + OFF_PDE + 128,  128, sm);
    float s20 = sumRange(ws + OFF_PDE + 256,  128, sm);
    float s21 = sumRange(ws + OFF_PDE + 384,  128, sm);
    float gx  = sumRange(ws + OFF_PDE + 512,  256, sm);
    float gy  = sumRange(ws + OFF_PDE + 768,  256, sm);
    float num = sumRange(ws + OFF_PDE + 1024, 256, sm);
    float den = sumRange(ws + OFF_PDE + 1280, 256, sm);
    if (threadIdx.x != 0) return;

    float chamfer = sch / (float)NPTS;       // (sum_minP + sum_minG)/NPTS
    float dsum = (2.f*i0 + 1e-5f) / (p0 + g0 + 1e-5f)
               + (2.f*i1 + 1e-5f) / (p1 + g1 + 1e-5f);
    float cldice = 1.f - 0.5f * dsum;
    float silog = 0.f;
    {
        float gm = sg0 / (float)DPIX;
        float gv = s20 / (float)DPIX - gm*gm;
        silog += 10.f*0.5f*gv + 10.f*0.5f*gm*gm;
        gm = sg1 / (float)DPIX;
        gv = s21 / (float)DPIX - gm*gm;
        silog += 10.f*0.5f*gv + 10.f*0.5f*gm*gm;
    }
    float grad_l1 = gx / (float)(B*(DHH-1)*DWW) + gy / (float)(B*DHH*(DWW-1));
    float mask_l1 = num / (den + 1e-8f);
    float dloss = silog + grad_l1 + mask_l1;
    int it = iter[0]; if (it < 1) it = 1;
    float gamma1 = 2.f * logf((float)it / 20000.f);
    out[0] = gamma1 * chamfer + 0.5f * cldice + 0.01f * dloss;
}

extern "C" void kernel_launch(void* const* d_in, const int* in_sizes, int n_in,
                              void* d_out, int out_size, void* d_ws, size_t ws_size,
                              hipStream_t stream) {
    const float* pc  = (const float*)d_in[0];
    const float* pv  = (const float*)d_in[1];
    const float* pd  = (const float*)d_in[2];
    const float* gp  = (const float*)d_in[3];
    const float* gvv = (const float*)d_in[4];
    const float* gd  = (const float*)d_in[5];
    const float* mk  = (const float*)d_in[6];
    const int*   it  = (const int*)d_in[7];
    float* ws  = (float*)d_ws;
    float* out = (float*)d_out;

    k_phase1<<<2816, 256, 0, stream>>>(pc, gp, pv, gvv, pd, gd, mk, ws);
    k_phase2<<<576,  256, 0, stream>>>(ws);
    k_final <<<1,    256, 0, stream>>>(ws, it, out);
}